// Round 10
// baseline (258.527 us; speedup 1.0000x reference)
//
#include <hip/hip_runtime.h>
#include <math.h>

#define CHI 64
#define CHO 64
#define HH 128
#define WW 128
#define NB 4
#define KK 9
#define NOFF 27
#define EPSV 1e-5f
#define PLANE (HH * WW)
#define SP 72                 // LDS ci-stride (shorts) for prep transpose tile

typedef float f32x4 __attribute__((ext_vector_type(4)));
typedef short bf16x8 __attribute__((ext_vector_type(8)));
typedef unsigned int u32x4 __attribute__((ext_vector_type(4)));

// fp32 -> bf16 round-to-nearest-even
__device__ __forceinline__ unsigned short f2bf(float f) {
    unsigned u = __float_as_uint(f);
    u += 0x7fff + ((u >> 16) & 1);
    return (unsigned short)(u >> 16);
}
__device__ __forceinline__ float bfl(unsigned u) { return __uint_as_float(u << 16); }
__device__ __forceinline__ float bfh(unsigned u) { return __uint_as_float(u & 0xffff0000u); }

// ---------------- fused prep: x-transpose (blocks 0..511) + weight pack (512..655) ----
// R6-EXACT REVERT. R7/R9 proved the "dense" transposes leave deform with
// FETCH 16MB / WRITE 52MB / +9us (cache-state poisoning); this version
// measured deform FETCH 4.7MB / 55.8us and total 138.1us. Do not touch.
__global__ __launch_bounds__(256) void prep_kernel(const float* __restrict__ x,
                                                   const float* __restrict__ w,
                                                   const float* __restrict__ w_off,
                                                   unsigned short* __restrict__ x_bf,
                                                   unsigned short* __restrict__ w_bf,
                                                   unsigned short* __restrict__ woA) {
    __shared__ unsigned short lt[128 * SP];    // 18432 B
    if (blockIdx.x < 512) {
        const int id = blockIdx.x;             // b*128 + y
        const int b  = id >> 7;
        const int y  = id & 127;
        const int t  = threadIdx.x;
        const int ci = t >> 2, qx = t & 3;
        const float* src = x + ((size_t)(b * CHI + ci)) * PLANE + y * WW;
#pragma unroll
        for (int it = 0; it < 8; it++) {
            int xcol = (it * 4 + qx) * 4;
            float4 v = *(const float4*)(src + xcol);
            lt[(xcol + 0) * SP + ci] = f2bf(v.x);
            lt[(xcol + 1) * SP + ci] = f2bf(v.y);
            lt[(xcol + 2) * SP + ci] = f2bf(v.z);
            lt[(xcol + 3) * SP + ci] = f2bf(v.w);
        }
        __syncthreads();
        unsigned short* dst = x_bf + (size_t)id * (WW * 64);
#pragma unroll
        for (int it = 0; it < 4; it++) {
            int px  = it * 32 + (t >> 3);
            int ci8 = t & 7;
            u32x4 v = *(const u32x4*)&lt[px * SP + ci8 * 8];
            *(u32x4*)(dst + px * 64 + ci8 * 8) = v;
        }
    } else {
        int i = (blockIdx.x - 512) * 256 + threadIdx.x;   // 144*256 = 36864 exactly
        {
            int j    = i & 7;
            int lane = (i >> 3) & 63;
            int ks   = (i >> 9) & 1;
            int ct   = (i >> 10) & 3;
            int kk   = i >> 12;                // 0..8
            int co   = ct * 16 + (lane & 15);
            int ci   = ks * 32 + ((lane >> 4) & 3) * 8 + j;
            w_bf[i]  = f2bf(w[(co * CHI + ci) * KK + kk]);
        }
        if (i < 18432) {
            int j    = i & 7;
            int lane = (i >> 3) & 63;
            int ct   = (i >> 9) & 1;
            int ks   = (i >> 10) & 1;
            int kk   = i >> 11;                // 0..8
            int c    = ct * 16 + (lane & 15);
            int ci   = ks * 32 + (lane >> 4) * 8 + j;
            woA[i]   = (c < NOFF) ? f2bf(w_off[(c * CHI + ci) * KK + kk]) : (unsigned short)0;
        }
    }
}

// ---------------- deform, co-split (R22) ----------------
// Grid 2048: bit3 = cohalf (which 32 of the 64 output channels). deform was
// GRID-limited at 4 blocks/CU (16/32 wave slots); co-split doubles resident
// waves. Gathers + offset-conv are duplicated across the two cohalf blocks
// (latency-bound, TA ~16% busy -> duplication is cheap parallelism); MFMA,
// acc, A-frags halve. To fit 8 blocks/CU the halo-LDS offset-conv becomes
// gather-style straight from x_bf (identical addresses/zero-fill -> bitwise-
// identical offsets; also deletes the 344K xs bank conflicts). LDS 7.9KB.
// Stats remain exact: channel split keeps per-block sum/sum^2 valid; pstats
// rows disjoint by cohalf; summation order preserved (bitwise-same output).
__global__ __launch_bounds__(256, 8) void deform_kernel(const unsigned short* __restrict__ x_bf,
                                                        const unsigned short* __restrict__ w_bf,
                                                        const unsigned short* __restrict__ woA,
                                                        const float* __restrict__ b_off,
                                                        float* __restrict__ out,
                                                        float* __restrict__ pstats) {
    const int id     = blockIdx.x;             // 0..2047
    const int slot   = id & 7;
    const int b      = slot >> 1;
    const int cohalf = (id >> 3) & 1;
    const int rb     = id >> 4;                // 0..127
    const int h      = (slot & 1) * 64 + (rb >> 1);
    const int whalf  = rb & 1;
    const int w0     = whalf * 64;
    const int pg     = slot + 8 * rb;          // pixel-group 0..1023 (pstats column)
    const int tid    = threadIdx.x;
    const int lane   = tid & 63;
    const int wave   = __builtin_amdgcn_readfirstlane(tid >> 6);
    const int quad   = lane >> 4, pxin = lane & 15;
    const int pxl    = wave * 16 + pxin;       // block-local pixel 0..63
    const int wpix   = w0 + pxl;               // this lane's x coordinate

    __shared__ float offs[64 * 27];            // 6912 B, stride 27 (conflict-free)
    __shared__ float red[2 * 4 * 32];          // 1024 B

    const unsigned short* xb  = x_bf + (size_t)b * (PLANE * 64);
    const unsigned short* xbq = xb + quad * 8;

    // ---- offset conv, gather-style: 27 channels x this wave's 16 px ----
    // Same values the halo-staged version produced (incl. zero-fill), same
    // MFMA order -> bitwise-identical offsets.
    f32x4 oacc0 = {0.f, 0.f, 0.f, 0.f};
    f32x4 oacc1 = {0.f, 0.f, 0.f, 0.f};
#pragma unroll 3
    for (int kk = 0; kk < KK; kk++) {
        const int ky = kk / 3, kx = kk - ky * 3;
        const int hr = h - 1 + ky;
        const int wc = wpix - 1 + kx;
        const bool ok = ((unsigned)hr < HH) && ((unsigned)wc < WW);
        const unsigned po = ok ? ((unsigned)(hr * WW + wc)) << 6 : 0u;
        bf16x8 Bv0 = {0, 0, 0, 0, 0, 0, 0, 0};
        bf16x8 Bv1 = {0, 0, 0, 0, 0, 0, 0, 0};
        if (ok) {
            Bv0 = *(const bf16x8*)(xbq + po);
            Bv1 = *(const bf16x8*)(xbq + po + 32);
        }
        const bf16x8* wa = (const bf16x8*)woA + (size_t)(kk * 4) * 64;
        bf16x8 A0k0 = wa[lane];
        bf16x8 A1k0 = wa[64 + lane];
        bf16x8 A0k1 = wa[128 + lane];
        bf16x8 A1k1 = wa[192 + lane];
        // ks=0 then ks=1, oacc0 before oacc1 (original order)
        oacc0 = __builtin_amdgcn_mfma_f32_16x16x32_bf16(A0k0, Bv0, oacc0, 0, 0, 0);
        oacc1 = __builtin_amdgcn_mfma_f32_16x16x32_bf16(A1k0, Bv0, oacc1, 0, 0, 0);
        oacc0 = __builtin_amdgcn_mfma_f32_16x16x32_bf16(A0k1, Bv1, oacc0, 0, 0, 0);
        oacc1 = __builtin_amdgcn_mfma_f32_16x16x32_bf16(A1k1, Bv1, oacc1, 0, 0, 0);
    }

    // ---- park offsets in LDS: offs[px_local][ch], stride 27 ----
#pragma unroll
    for (int r = 0; r < 4; r++) {
        int c0 = quad * 4 + r;
        offs[pxl * 27 + c0] = oacc0[r];
        int c1 = 16 + quad * 4 + r;
        if (c1 < NOFF) offs[pxl * 27 + c1] = oacc1[r];
    }
    __syncthreads();

    // ---- main gather + MFMA loop (gathers as before; MFMA halved to cohalf) ----
    f32x4 acc[2];
    acc[0] = (f32x4){0.f, 0.f, 0.f, 0.f};
    acc[1] = (f32x4){0.f, 0.f, 0.f, 0.f};

#pragma unroll 3
    for (int kk = 0; kk < KK; kk++) {
        const int ky = kk / 3, kx = kk - ky * 3;
        float dyv = offs[pxl * 27 + 2 * kk]     + b_off[2 * kk];
        float dxv = offs[pxl * 27 + 2 * kk + 1] + b_off[2 * kk + 1];
        float mov = offs[pxl * 27 + 18 + kk]    + b_off[18 + kk];

        float m   = 1.f / (1.f + __expf(-mov));
        float py  = (float)(h - 1 + ky) + dyv;
        float px_ = (float)(wpix - 1 + kx) + dxv;
        float fy0 = floorf(py), fx0 = floorf(px_);
        float wy = py - fy0, wx = px_ - fx0;
        int y0 = (int)fy0, x0 = (int)fx0;
        int y1 = y0 + 1, x1 = x0 + 1;
        bool vy0 = (unsigned)y0 < HH, vy1 = (unsigned)y1 < HH;
        bool vx0 = (unsigned)x0 < WW, vx1 = (unsigned)x1 < WW;
        float a00 = (vy0 && vx0) ? (1.f - wy) * (1.f - wx) * m : 0.f;
        float a01 = (vy0 && vx1) ? (1.f - wy) * wx * m : 0.f;
        float a10 = (vy1 && vx0) ? wy * (1.f - wx) * m : 0.f;
        float a11 = (vy1 && vx1) ? wy * wx * m : 0.f;
        int cy0 = min(max(y0, 0), HH - 1), cy1 = min(max(y1, 0), HH - 1);
        int cx0 = min(max(x0, 0), WW - 1), cx1 = min(max(x1, 0), WW - 1);
        const unsigned o00 = ((unsigned)(cy0 * WW + cx0)) << 6;
        const unsigned o01 = ((unsigned)(cy0 * WW + cx1)) << 6;
        const unsigned o10 = ((unsigned)(cy1 * WW + cx0)) << 6;
        const unsigned o11 = ((unsigned)(cy1 * WW + cx1)) << 6;

        u32x4 g00a = *(const u32x4*)(xbq + o00);
        u32x4 g01a = *(const u32x4*)(xbq + o01);
        u32x4 g10a = *(const u32x4*)(xbq + o10);
        u32x4 g11a = *(const u32x4*)(xbq + o11);
        u32x4 g00b = *(const u32x4*)(xbq + o00 + 32);
        u32x4 g01b = *(const u32x4*)(xbq + o01 + 32);
        u32x4 g10b = *(const u32x4*)(xbq + o10 + 32);
        u32x4 g11b = *(const u32x4*)(xbq + o11 + 32);

        // A fragments: only this block's 2 co-tiles (frag q = ct*2+ks)
        const bf16x8* wb = (const bf16x8*)w_bf + (size_t)(kk * 8) * 64;
        bf16x8 A00 = wb[((2 * cohalf + 0) * 2 + 0) * 64 + lane];
        bf16x8 A01 = wb[((2 * cohalf + 0) * 2 + 1) * 64 + lane];
        bf16x8 A10 = wb[((2 * cohalf + 1) * 2 + 0) * 64 + lane];
        bf16x8 A11 = wb[((2 * cohalf + 1) * 2 + 1) * 64 + lane];

        bf16x8 B0, B1;
#pragma unroll
        for (int d = 0; d < 4; d++) {
            float tl = a00 * bfl(g00a[d]) + a01 * bfl(g01a[d])
                     + a10 * bfl(g10a[d]) + a11 * bfl(g11a[d]);
            float th = a00 * bfh(g00a[d]) + a01 * bfh(g01a[d])
                     + a10 * bfh(g10a[d]) + a11 * bfh(g11a[d]);
            B0[2 * d]     = (short)f2bf(tl);
            B0[2 * d + 1] = (short)f2bf(th);
            float ul = a00 * bfl(g00b[d]) + a01 * bfl(g01b[d])
                     + a10 * bfl(g10b[d]) + a11 * bfl(g11b[d]);
            float uh = a00 * bfh(g00b[d]) + a01 * bfh(g01b[d])
                     + a10 * bfh(g10b[d]) + a11 * bfh(g11b[d]);
            B1[2 * d]     = (short)f2bf(ul);
            B1[2 * d + 1] = (short)f2bf(uh);
        }

        // per-acc order B0 then B1 (original order per co-tile)
        acc[0] = __builtin_amdgcn_mfma_f32_16x16x32_bf16(A00, B0, acc[0], 0, 0, 0);
        acc[0] = __builtin_amdgcn_mfma_f32_16x16x32_bf16(A01, B1, acc[0], 0, 0, 0);
        acc[1] = __builtin_amdgcn_mfma_f32_16x16x32_bf16(A10, B0, acc[1], 0, 0, 0);
        acc[1] = __builtin_amdgcn_mfma_f32_16x16x32_bf16(A11, B1, acc[1], 0, 0, 0);
    }

    // ---- output write: co = (2*cohalf+t)*16 + quad*4 + r ----
#pragma unroll
    for (int t = 0; t < 2; t++) {
#pragma unroll
        for (int r = 0; r < 4; r++) {
            int co = (2 * cohalf + t) * 16 + quad * 4 + r;
            out[(((size_t)b * CHO + co) * HH + h) * WW + wpix] = acc[t][r];
        }
    }

    // ---- per-block channel stats over this block's 64 px, 32 co ----
#pragma unroll
    for (int t = 0; t < 2; t++) {
#pragma unroll
        for (int r = 0; r < 4; r++) {
            float s  = acc[t][r];
            float s2 = s * s;
#pragma unroll
            for (int mk = 1; mk < 16; mk <<= 1) {
                s  += __shfl_xor(s, mk, 64);
                s2 += __shfl_xor(s2, mk, 64);
            }
            if (pxin == 0) {
                int cl = t * 16 + quad * 4 + r;   // co_local 0..31
                red[(0 * 4 + wave) * 32 + cl] = s;
                red[(1 * 4 + wave) * 32 + cl] = s2;
            }
        }
    }
    __syncthreads();
    if (tid < 64) {
        int part = tid >> 5, idx = tid & 31;
        float v = red[(part * 4 + 0) * 32 + idx] + red[(part * 4 + 1) * 32 + idx]
                + red[(part * 4 + 2) * 32 + idx] + red[(part * 4 + 3) * 32 + idx];
        pstats[(size_t)(part * 64 + cohalf * 32 + idx) * 1024 + pg] = v;
    }
}

// ---------------- fused stats-reduce + BN + ReLU ----------------
// Verbatim R18 (passing).
__global__ __launch_bounds__(256) void statsbn_kernel(float* __restrict__ y,
                                                      const float* __restrict__ pstats,
                                                      const float* __restrict__ bias,
                                                      const float* __restrict__ gamma,
                                                      const float* __restrict__ beta) {
    const int co  = blockIdx.x & 63;
    const int seg = blockIdx.x >> 6;           // 0..7
    const int t   = threadIdx.x;

    const float* ps  = pstats + (size_t)co * 1024;
    const float* ps2 = pstats + (size_t)(64 + co) * 1024;
    float s  = ps[t]  + ps[t + 256]  + ps[t + 512]  + ps[t + 768];
    float s2 = ps2[t] + ps2[t + 256] + ps2[t + 512] + ps2[t + 768];
#pragma unroll
    for (int o = 32; o > 0; o >>= 1) {
        s  += __shfl_down(s, o, 64);
        s2 += __shfl_down(s2, o, 64);
    }
    __shared__ float ls[8];
    int lane = t & 63, wv = t >> 6;
    if (lane == 0) { ls[wv] = s; ls[4 + wv] = s2; }
    __syncthreads();
    float S0 = ls[0] + ls[1] + ls[2] + ls[3];
    float S2 = ls[4] + ls[5] + ls[6] + ls[7];
    float bi = bias[co];
    float Sb  = S0 + 65536.f * bi;                       // sum(v+b)
    float S2b = S2 + 2.f * bi * S0 + 65536.f * bi * bi;  // sum((v+b)^2)
    const float inv_n = 1.f / 65536.f;
    float mean = Sb * inv_n;
    float var  = S2b * inv_n - mean * mean;
    float sc = gamma[co] * rsqrtf(var + EPSV);
    float sh = beta[co] - mean * sc + bi * sc;           // y stored raw

    const int b = seg >> 1, half = seg & 1;
    float4* p = (float4*)(y + ((size_t)(b * CHO + co)) * PLANE + half * 8192);
#pragma unroll
    for (int it = 0; it < 8; it++) {
        float4 v = p[it * 256 + t];
        v.x = fmaxf(fmaf(v.x, sc, sh), 0.f);
        v.y = fmaxf(fmaf(v.y, sc, sh), 0.f);
        v.z = fmaxf(fmaf(v.z, sc, sh), 0.f);
        v.w = fmaxf(fmaf(v.w, sc, sh), 0.f);
        p[it * 256 + t] = v;
    }
}

extern "C" void kernel_launch(void* const* d_in, const int* in_sizes, int n_in,
                              void* d_out, int out_size, void* d_ws, size_t ws_size,
                              hipStream_t stream) {
    const float* x     = (const float*)d_in[0];
    const float* w_off = (const float*)d_in[1];
    const float* b_off = (const float*)d_in[2];
    const float* wmat  = (const float*)d_in[3];
    const float* bvec  = (const float*)d_in[4];
    const float* gamma = (const float*)d_in[5];
    const float* beta  = (const float*)d_in[6];
    float* out = (float*)d_out;

    char* ws = (char*)d_ws;
    unsigned short* w_bf  = (unsigned short*)(ws + 1024);   // 73728 B
    unsigned short* woA   = (unsigned short*)(ws + 74752);  // 36864 B
    unsigned short* x_bf  = (unsigned short*)(ws + 139264); // 8388608 B
    float* pstats         = (float*)(ws + 8527872);         // 524288 B -> 9052160 total

    prep_kernel<<<656, 256, 0, stream>>>(x, wmat, w_off, x_bf, w_bf, woA);
    deform_kernel<<<2048, 256, 0, stream>>>(x_bf, w_bf, woA, b_off, out, pstats);
    statsbn_kernel<<<512, 256, 0, stream>>>(out, pstats, bvec, gamma, beta);
}

// Round 11
// 190.523 us; speedup vs baseline: 1.3569x; 1.3569x over previous
//
#include <hip/hip_runtime.h>
#include <math.h>

#define CHI 64
#define CHO 64
#define HH 128
#define WW 128
#define NB 4
#define KK 9
#define NOFF 27
#define EPSV 1e-5f
#define PLANE (HH * WW)
#define SP 72                 // LDS ci-stride (shorts) for prep transpose tile

typedef float f32x4 __attribute__((ext_vector_type(4)));
typedef short bf16x8 __attribute__((ext_vector_type(8)));
typedef unsigned int u32x4 __attribute__((ext_vector_type(4)));

// fp32 -> bf16 round-to-nearest-even
__device__ __forceinline__ unsigned short f2bf(float f) {
    unsigned u = __float_as_uint(f);
    u += 0x7fff + ((u >> 16) & 1);
    return (unsigned short)(u >> 16);
}
__device__ __forceinline__ float bfl(unsigned u) { return __uint_as_float(u << 16); }
__device__ __forceinline__ float bfh(unsigned u) { return __uint_as_float(u & 0xffff0000u); }

// ---------------- fused prep: x-transpose (blocks 0..511) + weight pack (512..655) ----
// R6-EXACT. R7/R9 proved dense-transpose variants poison deform's cache state
// (FETCH 4.7->16MB, +9us). Do not touch.
__global__ __launch_bounds__(256) void prep_kernel(const float* __restrict__ x,
                                                   const float* __restrict__ w,
                                                   const float* __restrict__ w_off,
                                                   unsigned short* __restrict__ x_bf,
                                                   unsigned short* __restrict__ w_bf,
                                                   unsigned short* __restrict__ woA) {
    __shared__ unsigned short lt[128 * SP];    // 18432 B
    if (blockIdx.x < 512) {
        const int id = blockIdx.x;             // b*128 + y
        const int b  = id >> 7;
        const int y  = id & 127;
        const int t  = threadIdx.x;
        const int ci = t >> 2, qx = t & 3;
        const float* src = x + ((size_t)(b * CHI + ci)) * PLANE + y * WW;
#pragma unroll
        for (int it = 0; it < 8; it++) {
            int xcol = (it * 4 + qx) * 4;
            float4 v = *(const float4*)(src + xcol);
            lt[(xcol + 0) * SP + ci] = f2bf(v.x);
            lt[(xcol + 1) * SP + ci] = f2bf(v.y);
            lt[(xcol + 2) * SP + ci] = f2bf(v.z);
            lt[(xcol + 3) * SP + ci] = f2bf(v.w);
        }
        __syncthreads();
        unsigned short* dst = x_bf + (size_t)id * (WW * 64);
#pragma unroll
        for (int it = 0; it < 4; it++) {
            int px  = it * 32 + (t >> 3);
            int ci8 = t & 7;
            u32x4 v = *(const u32x4*)&lt[px * SP + ci8 * 8];
            *(u32x4*)(dst + px * 64 + ci8 * 8) = v;
        }
    } else {
        int i = (blockIdx.x - 512) * 256 + threadIdx.x;   // 144*256 = 36864 exactly
        {
            int j    = i & 7;
            int lane = (i >> 3) & 63;
            int ks   = (i >> 9) & 1;
            int ct   = (i >> 10) & 3;
            int kk   = i >> 12;                // 0..8
            int co   = ct * 16 + (lane & 15);
            int ci   = ks * 32 + ((lane >> 4) & 3) * 8 + j;
            w_bf[i]  = f2bf(w[(co * CHI + ci) * KK + kk]);
        }
        if (i < 18432) {
            int j    = i & 7;
            int lane = (i >> 3) & 63;
            int ct   = (i >> 9) & 1;
            int ks   = (i >> 10) & 1;
            int kk   = i >> 11;                // 0..8
            int c    = ct * 16 + (lane & 15);
            int ci   = ks * 32 + (lane >> 4) * 8 + j;
            woA[i]   = (c < NOFF) ? f2bf(w_off[(c * CHI + ci) * KK + kk]) : (unsigned short)0;
        }
    }
}

// ---------------- deform, co-split (R23 = R22 at the feasible reg point) ----
// R22's (256,8) demanded 64 unified regs/wave -> compiler spilled the gather
// batch to scratch (VGPR=32, WRITE 309MB, 180us) BUT proved 8-block
// co-residency works (occupancy 67%). The wave x reg product is the
// constraint: 512/EU. This round: (256,6) -> 24 waves/CU (1.5x R18) with
// ~85 regs/wave, enough for the ~80-reg live set. Everything else R22-exact
// (bitwise-correct there): gather-style offset conv, LDS 8KB, co-split
// grid 2048, stats rows disjoint by cohalf.
__global__ __launch_bounds__(256, 6) void deform_kernel(const unsigned short* __restrict__ x_bf,
                                                        const unsigned short* __restrict__ w_bf,
                                                        const unsigned short* __restrict__ woA,
                                                        const float* __restrict__ b_off,
                                                        float* __restrict__ out,
                                                        float* __restrict__ pstats) {
    const int id     = blockIdx.x;             // 0..2047
    const int slot   = id & 7;
    const int b      = slot >> 1;
    const int cohalf = (id >> 3) & 1;
    const int rb     = id >> 4;                // 0..127
    const int h      = (slot & 1) * 64 + (rb >> 1);
    const int whalf  = rb & 1;
    const int w0     = whalf * 64;
    const int pg     = slot + 8 * rb;          // pixel-group 0..1023 (pstats column)
    const int tid    = threadIdx.x;
    const int lane   = tid & 63;
    const int wave   = __builtin_amdgcn_readfirstlane(tid >> 6);
    const int quad   = lane >> 4, pxin = lane & 15;
    const int pxl    = wave * 16 + pxin;       // block-local pixel 0..63
    const int wpix   = w0 + pxl;               // this lane's x coordinate

    __shared__ float offs[64 * 27];            // 6912 B, stride 27 (conflict-free)
    __shared__ float red[2 * 4 * 32];          // 1024 B

    const unsigned short* xb  = x_bf + (size_t)b * (PLANE * 64);
    const unsigned short* xbq = xb + quad * 8;

    // ---- offset conv, gather-style: 27 channels x this wave's 16 px ----
    f32x4 oacc0 = {0.f, 0.f, 0.f, 0.f};
    f32x4 oacc1 = {0.f, 0.f, 0.f, 0.f};
#pragma unroll 3
    for (int kk = 0; kk < KK; kk++) {
        const int ky = kk / 3, kx = kk - ky * 3;
        const int hr = h - 1 + ky;
        const int wc = wpix - 1 + kx;
        const bool ok = ((unsigned)hr < HH) && ((unsigned)wc < WW);
        const unsigned po = ok ? ((unsigned)(hr * WW + wc)) << 6 : 0u;
        bf16x8 Bv0 = {0, 0, 0, 0, 0, 0, 0, 0};
        bf16x8 Bv1 = {0, 0, 0, 0, 0, 0, 0, 0};
        if (ok) {
            Bv0 = *(const bf16x8*)(xbq + po);
            Bv1 = *(const bf16x8*)(xbq + po + 32);
        }
        const bf16x8* wa = (const bf16x8*)woA + (size_t)(kk * 4) * 64;
        bf16x8 A0k0 = wa[lane];
        bf16x8 A1k0 = wa[64 + lane];
        bf16x8 A0k1 = wa[128 + lane];
        bf16x8 A1k1 = wa[192 + lane];
        oacc0 = __builtin_amdgcn_mfma_f32_16x16x32_bf16(A0k0, Bv0, oacc0, 0, 0, 0);
        oacc1 = __builtin_amdgcn_mfma_f32_16x16x32_bf16(A1k0, Bv0, oacc1, 0, 0, 0);
        oacc0 = __builtin_amdgcn_mfma_f32_16x16x32_bf16(A0k1, Bv1, oacc0, 0, 0, 0);
        oacc1 = __builtin_amdgcn_mfma_f32_16x16x32_bf16(A1k1, Bv1, oacc1, 0, 0, 0);
    }

    // ---- park offsets in LDS: offs[px_local][ch], stride 27 ----
#pragma unroll
    for (int r = 0; r < 4; r++) {
        int c0 = quad * 4 + r;
        offs[pxl * 27 + c0] = oacc0[r];
        int c1 = 16 + quad * 4 + r;
        if (c1 < NOFF) offs[pxl * 27 + c1] = oacc1[r];
    }
    __syncthreads();

    // ---- main gather + MFMA loop (gathers full; MFMA halved to cohalf) ----
    f32x4 acc[2];
    acc[0] = (f32x4){0.f, 0.f, 0.f, 0.f};
    acc[1] = (f32x4){0.f, 0.f, 0.f, 0.f};

#pragma unroll 3
    for (int kk = 0; kk < KK; kk++) {
        const int ky = kk / 3, kx = kk - ky * 3;
        float dyv = offs[pxl * 27 + 2 * kk]     + b_off[2 * kk];
        float dxv = offs[pxl * 27 + 2 * kk + 1] + b_off[2 * kk + 1];
        float mov = offs[pxl * 27 + 18 + kk]    + b_off[18 + kk];

        float m   = 1.f / (1.f + __expf(-mov));
        float py  = (float)(h - 1 + ky) + dyv;
        float px_ = (float)(wpix - 1 + kx) + dxv;
        float fy0 = floorf(py), fx0 = floorf(px_);
        float wy = py - fy0, wx = px_ - fx0;
        int y0 = (int)fy0, x0 = (int)fx0;
        int y1 = y0 + 1, x1 = x0 + 1;
        bool vy0 = (unsigned)y0 < HH, vy1 = (unsigned)y1 < HH;
        bool vx0 = (unsigned)x0 < WW, vx1 = (unsigned)x1 < WW;
        float a00 = (vy0 && vx0) ? (1.f - wy) * (1.f - wx) * m : 0.f;
        float a01 = (vy0 && vx1) ? (1.f - wy) * wx * m : 0.f;
        float a10 = (vy1 && vx0) ? wy * (1.f - wx) * m : 0.f;
        float a11 = (vy1 && vx1) ? wy * wx * m : 0.f;
        int cy0 = min(max(y0, 0), HH - 1), cy1 = min(max(y1, 0), HH - 1);
        int cx0 = min(max(x0, 0), WW - 1), cx1 = min(max(x1, 0), WW - 1);
        const unsigned o00 = ((unsigned)(cy0 * WW + cx0)) << 6;
        const unsigned o01 = ((unsigned)(cy0 * WW + cx1)) << 6;
        const unsigned o10 = ((unsigned)(cy1 * WW + cx0)) << 6;
        const unsigned o11 = ((unsigned)(cy1 * WW + cx1)) << 6;

        u32x4 g00a = *(const u32x4*)(xbq + o00);
        u32x4 g01a = *(const u32x4*)(xbq + o01);
        u32x4 g10a = *(const u32x4*)(xbq + o10);
        u32x4 g11a = *(const u32x4*)(xbq + o11);
        u32x4 g00b = *(const u32x4*)(xbq + o00 + 32);
        u32x4 g01b = *(const u32x4*)(xbq + o01 + 32);
        u32x4 g10b = *(const u32x4*)(xbq + o10 + 32);
        u32x4 g11b = *(const u32x4*)(xbq + o11 + 32);

        const bf16x8* wb = (const bf16x8*)w_bf + (size_t)(kk * 8) * 64;
        bf16x8 A00 = wb[((2 * cohalf + 0) * 2 + 0) * 64 + lane];
        bf16x8 A01 = wb[((2 * cohalf + 0) * 2 + 1) * 64 + lane];
        bf16x8 A10 = wb[((2 * cohalf + 1) * 2 + 0) * 64 + lane];
        bf16x8 A11 = wb[((2 * cohalf + 1) * 2 + 1) * 64 + lane];

        bf16x8 B0, B1;
#pragma unroll
        for (int d = 0; d < 4; d++) {
            float tl = a00 * bfl(g00a[d]) + a01 * bfl(g01a[d])
                     + a10 * bfl(g10a[d]) + a11 * bfl(g11a[d]);
            float th = a00 * bfh(g00a[d]) + a01 * bfh(g01a[d])
                     + a10 * bfh(g10a[d]) + a11 * bfh(g11a[d]);
            B0[2 * d]     = (short)f2bf(tl);
            B0[2 * d + 1] = (short)f2bf(th);
            float ul = a00 * bfl(g00b[d]) + a01 * bfl(g01b[d])
                     + a10 * bfl(g10b[d]) + a11 * bfl(g11b[d]);
            float uh = a00 * bfh(g00b[d]) + a01 * bfh(g01b[d])
                     + a10 * bfh(g10b[d]) + a11 * bfh(g11b[d]);
            B1[2 * d]     = (short)f2bf(ul);
            B1[2 * d + 1] = (short)f2bf(uh);
        }

        acc[0] = __builtin_amdgcn_mfma_f32_16x16x32_bf16(A00, B0, acc[0], 0, 0, 0);
        acc[0] = __builtin_amdgcn_mfma_f32_16x16x32_bf16(A01, B1, acc[0], 0, 0, 0);
        acc[1] = __builtin_amdgcn_mfma_f32_16x16x32_bf16(A10, B0, acc[1], 0, 0, 0);
        acc[1] = __builtin_amdgcn_mfma_f32_16x16x32_bf16(A11, B1, acc[1], 0, 0, 0);
    }

    // ---- output write: co = (2*cohalf+t)*16 + quad*4 + r ----
#pragma unroll
    for (int t = 0; t < 2; t++) {
#pragma unroll
        for (int r = 0; r < 4; r++) {
            int co = (2 * cohalf + t) * 16 + quad * 4 + r;
            out[(((size_t)b * CHO + co) * HH + h) * WW + wpix] = acc[t][r];
        }
    }

    // ---- per-block channel stats over this block's 64 px, 32 co ----
#pragma unroll
    for (int t = 0; t < 2; t++) {
#pragma unroll
        for (int r = 0; r < 4; r++) {
            float s  = acc[t][r];
            float s2 = s * s;
#pragma unroll
            for (int mk = 1; mk < 16; mk <<= 1) {
                s  += __shfl_xor(s, mk, 64);
                s2 += __shfl_xor(s2, mk, 64);
            }
            if (pxin == 0) {
                int cl = t * 16 + quad * 4 + r;   // co_local 0..31
                red[(0 * 4 + wave) * 32 + cl] = s;
                red[(1 * 4 + wave) * 32 + cl] = s2;
            }
        }
    }
    __syncthreads();
    if (tid < 64) {
        int part = tid >> 5, idx = tid & 31;
        float v = red[(part * 4 + 0) * 32 + idx] + red[(part * 4 + 1) * 32 + idx]
                + red[(part * 4 + 2) * 32 + idx] + red[(part * 4 + 3) * 32 + idx];
        pstats[(size_t)(part * 64 + cohalf * 32 + idx) * 1024 + pg] = v;
    }
}

// ---------------- fused stats-reduce + BN + ReLU ----------------
// Verbatim R18 (passing).
__global__ __launch_bounds__(256) void statsbn_kernel(float* __restrict__ y,
                                                      const float* __restrict__ pstats,
                                                      const float* __restrict__ bias,
                                                      const float* __restrict__ gamma,
                                                      const float* __restrict__ beta) {
    const int co  = blockIdx.x & 63;
    const int seg = blockIdx.x >> 6;           // 0..7
    const int t   = threadIdx.x;

    const float* ps  = pstats + (size_t)co * 1024;
    const float* ps2 = pstats + (size_t)(64 + co) * 1024;
    float s  = ps[t]  + ps[t + 256]  + ps[t + 512]  + ps[t + 768];
    float s2 = ps2[t] + ps2[t + 256] + ps2[t + 512] + ps2[t + 768];
#pragma unroll
    for (int o = 32; o > 0; o >>= 1) {
        s  += __shfl_down(s, o, 64);
        s2 += __shfl_down(s2, o, 64);
    }
    __shared__ float ls[8];
    int lane = t & 63, wv = t >> 6;
    if (lane == 0) { ls[wv] = s; ls[4 + wv] = s2; }
    __syncthreads();
    float S0 = ls[0] + ls[1] + ls[2] + ls[3];
    float S2 = ls[4] + ls[5] + ls[6] + ls[7];
    float bi = bias[co];
    float Sb  = S0 + 65536.f * bi;                       // sum(v+b)
    float S2b = S2 + 2.f * bi * S0 + 65536.f * bi * bi;  // sum((v+b)^2)
    const float inv_n = 1.f / 65536.f;
    float mean = Sb * inv_n;
    float var  = S2b * inv_n - mean * mean;
    float sc = gamma[co] * rsqrtf(var + EPSV);
    float sh = beta[co] - mean * sc + bi * sc;           // y stored raw

    const int b = seg >> 1, half = seg & 1;
    float4* p = (float4*)(y + ((size_t)(b * CHO + co)) * PLANE + half * 8192);
#pragma unroll
    for (int it = 0; it < 8; it++) {
        float4 v = p[it * 256 + t];
        v.x = fmaxf(fmaf(v.x, sc, sh), 0.f);
        v.y = fmaxf(fmaf(v.y, sc, sh), 0.f);
        v.z = fmaxf(fmaf(v.z, sc, sh), 0.f);
        v.w = fmaxf(fmaf(v.w, sc, sh), 0.f);
        p[it * 256 + t] = v;
    }
}

extern "C" void kernel_launch(void* const* d_in, const int* in_sizes, int n_in,
                              void* d_out, int out_size, void* d_ws, size_t ws_size,
                              hipStream_t stream) {
    const float* x     = (const float*)d_in[0];
    const float* w_off = (const float*)d_in[1];
    const float* b_off = (const float*)d_in[2];
    const float* wmat  = (const float*)d_in[3];
    const float* bvec  = (const float*)d_in[4];
    const float* gamma = (const float*)d_in[5];
    const float* beta  = (const float*)d_in[6];
    float* out = (float*)d_out;

    char* ws = (char*)d_ws;
    unsigned short* w_bf  = (unsigned short*)(ws + 1024);   // 73728 B
    unsigned short* woA   = (unsigned short*)(ws + 74752);  // 36864 B
    unsigned short* x_bf  = (unsigned short*)(ws + 139264); // 8388608 B
    float* pstats         = (float*)(ws + 8527872);         // 524288 B -> 9052160 total

    prep_kernel<<<656, 256, 0, stream>>>(x, wmat, w_off, x_bf, w_bf, woA);
    deform_kernel<<<2048, 256, 0, stream>>>(x_bf, w_bf, woA, b_off, out, pstats);
    statsbn_kernel<<<512, 256, 0, stream>>>(out, pstats, bvec, gamma, beta);
}

// Round 12
// 143.552 us; speedup vs baseline: 1.8009x; 1.3272x over previous
//
#include <hip/hip_runtime.h>
#include <math.h>

#define CHI 64
#define CHO 64
#define HH 128
#define WW 128
#define NB 4
#define KK 9
#define NOFF 27
#define EPSV 1e-5f
#define PLANE (HH * WW)
#define SP 72                 // LDS ci-stride (shorts) for prep transpose tile

typedef float f32x4 __attribute__((ext_vector_type(4)));
typedef short bf16x8 __attribute__((ext_vector_type(8)));
typedef unsigned int u32x4 __attribute__((ext_vector_type(4)));

// fp32 -> bf16 round-to-nearest-even
__device__ __forceinline__ unsigned short f2bf(float f) {
    unsigned u = __float_as_uint(f);
    u += 0x7fff + ((u >> 16) & 1);
    return (unsigned short)(u >> 16);
}
__device__ __forceinline__ float bfl(unsigned u) { return __uint_as_float(u << 16); }
__device__ __forceinline__ float bfh(unsigned u) { return __uint_as_float(u & 0xffff0000u); }

// ---------------- fused prep: x-transpose (blocks 0..511) + weight pack (512..655) ----
// R6-EXACT. R7/R9 proved dense-transpose variants poison deform's cache state
// (FETCH 4.7->16MB, +9us). Do not touch.
__global__ __launch_bounds__(256) void prep_kernel(const float* __restrict__ x,
                                                   const float* __restrict__ w,
                                                   const float* __restrict__ w_off,
                                                   unsigned short* __restrict__ x_bf,
                                                   unsigned short* __restrict__ w_bf,
                                                   unsigned short* __restrict__ woA) {
    __shared__ unsigned short lt[128 * SP];    // 18432 B
    if (blockIdx.x < 512) {
        const int id = blockIdx.x;             // b*128 + y
        const int b  = id >> 7;
        const int y  = id & 127;
        const int t  = threadIdx.x;
        const int ci = t >> 2, qx = t & 3;
        const float* src = x + ((size_t)(b * CHI + ci)) * PLANE + y * WW;
#pragma unroll
        for (int it = 0; it < 8; it++) {
            int xcol = (it * 4 + qx) * 4;
            float4 v = *(const float4*)(src + xcol);
            lt[(xcol + 0) * SP + ci] = f2bf(v.x);
            lt[(xcol + 1) * SP + ci] = f2bf(v.y);
            lt[(xcol + 2) * SP + ci] = f2bf(v.z);
            lt[(xcol + 3) * SP + ci] = f2bf(v.w);
        }
        __syncthreads();
        unsigned short* dst = x_bf + (size_t)id * (WW * 64);
#pragma unroll
        for (int it = 0; it < 4; it++) {
            int px  = it * 32 + (t >> 3);
            int ci8 = t & 7;
            u32x4 v = *(const u32x4*)&lt[px * SP + ci8 * 8];
            *(u32x4*)(dst + px * 64 + ci8 * 8) = v;
        }
    } else {
        int i = (blockIdx.x - 512) * 256 + threadIdx.x;   // 144*256 = 36864 exactly
        {
            int j    = i & 7;
            int lane = (i >> 3) & 63;
            int ks   = (i >> 9) & 1;
            int ct   = (i >> 10) & 3;
            int kk   = i >> 12;                // 0..8
            int co   = ct * 16 + (lane & 15);
            int ci   = ks * 32 + ((lane >> 4) & 3) * 8 + j;
            w_bf[i]  = f2bf(w[(co * CHI + ci) * KK + kk]);
        }
        if (i < 18432) {
            int j    = i & 7;
            int lane = (i >> 3) & 63;
            int ct   = (i >> 9) & 1;
            int ks   = (i >> 10) & 1;
            int kk   = i >> 11;                // 0..8
            int c    = ct * 16 + (lane & 15);
            int ci   = ks * 32 + (lane >> 4) * 8 + j;
            woA[i]   = (c < NOFF) ? f2bf(w_off[(c * CHI + ci) * KK + kk]) : (unsigned short)0;
        }
    }
}

// ---------------- deform (R24 = R18 structure + gather-style offset conv) ----
// R18-exact grid/bounds/stats (1024 blocks, (256,4), full 64-co MFMA/block --
// the proven no-spill operating point; R22/R23 showed hipcc spills any higher
// occupancy target). ONE change: the halo-LDS offset-conv phase is replaced
// by the gather-style version verified bitwise in R22/R23 (same addresses,
// same zero-fill, same MFMA order). Deletes the 3x66x64 staging loop, two
// barriers, the 28.5KB xs array (LDS 37.9->8KB) and its 344K bank conflicts.
// Off-conv gathers hit the same 64B lines the main loop reads -> L2-warm.
__global__ __launch_bounds__(256, 4) void deform_kernel(const unsigned short* __restrict__ x_bf,
                                                        const unsigned short* __restrict__ w_bf,
                                                        const unsigned short* __restrict__ woA,
                                                        const float* __restrict__ b_off,
                                                        float* __restrict__ out,
                                                        float* __restrict__ pstats) {
    const int id    = blockIdx.x;              // 0..1023
    const int slot  = id & 7;
    const int b     = slot >> 1;
    const int rb    = id >> 3;                 // 0..127
    const int h     = (slot & 1) * 64 + (rb >> 1);
    const int whalf = rb & 1;
    const int w0    = whalf * 64;
    const int tid   = threadIdx.x;
    const int lane  = tid & 63;
    const int wave  = __builtin_amdgcn_readfirstlane(tid >> 6);
    const int quad  = lane >> 4, pxin = lane & 15;
    const int pxl   = wave * 16 + pxin;        // block-local pixel 0..63
    const int wpix  = w0 + pxl;                // this lane's x coordinate

    __shared__ float offs[64 * 27];            // 6912 B, stride 27 (conflict-free)
    __shared__ float red[512];                 // 2048 B

    const unsigned short* xb  = x_bf + (size_t)b * (PLANE * 64);
    const unsigned short* xbq = xb + quad * 8;

    // ---- offset conv, gather-style: 27 channels x this wave's 16 px ----
    // Bitwise-identical inputs/order to the halo-staged R18 version.
    f32x4 oacc0 = {0.f, 0.f, 0.f, 0.f};
    f32x4 oacc1 = {0.f, 0.f, 0.f, 0.f};
#pragma unroll 3
    for (int kk = 0; kk < KK; kk++) {
        const int ky = kk / 3, kx = kk - ky * 3;
        const int hr = h - 1 + ky;
        const int wc = wpix - 1 + kx;
        const bool ok = ((unsigned)hr < HH) && ((unsigned)wc < WW);
        const unsigned po = ok ? ((unsigned)(hr * WW + wc)) << 6 : 0u;
        bf16x8 Bv0 = {0, 0, 0, 0, 0, 0, 0, 0};
        bf16x8 Bv1 = {0, 0, 0, 0, 0, 0, 0, 0};
        if (ok) {
            Bv0 = *(const bf16x8*)(xbq + po);
            Bv1 = *(const bf16x8*)(xbq + po + 32);
        }
        const bf16x8* wa = (const bf16x8*)woA + (size_t)(kk * 4) * 64;
        bf16x8 A0k0 = wa[lane];
        bf16x8 A1k0 = wa[64 + lane];
        bf16x8 A0k1 = wa[128 + lane];
        bf16x8 A1k1 = wa[192 + lane];
        oacc0 = __builtin_amdgcn_mfma_f32_16x16x32_bf16(A0k0, Bv0, oacc0, 0, 0, 0);
        oacc1 = __builtin_amdgcn_mfma_f32_16x16x32_bf16(A1k0, Bv0, oacc1, 0, 0, 0);
        oacc0 = __builtin_amdgcn_mfma_f32_16x16x32_bf16(A0k1, Bv1, oacc0, 0, 0, 0);
        oacc1 = __builtin_amdgcn_mfma_f32_16x16x32_bf16(A1k1, Bv1, oacc1, 0, 0, 0);
    }

    // ---- park offsets in LDS: offs[px_local][ch], stride 27 ----
#pragma unroll
    for (int r = 0; r < 4; r++) {
        int c0 = quad * 4 + r;
        offs[pxl * 27 + c0] = oacc0[r];
        int c1 = 16 + quad * 4 + r;
        if (c1 < NOFF) offs[pxl * 27 + c1] = oacc1[r];
    }
    __syncthreads();

    // ---- main gather + MFMA loop (R18-exact) ----
    f32x4 acc[4];
#pragma unroll
    for (int t = 0; t < 4; t++) acc[t] = (f32x4){0.f, 0.f, 0.f, 0.f};

#pragma unroll 3
    for (int kk = 0; kk < KK; kk++) {
        const int ky = kk / 3, kx = kk - ky * 3;
        float dyv = offs[pxl * 27 + 2 * kk]     + b_off[2 * kk];
        float dxv = offs[pxl * 27 + 2 * kk + 1] + b_off[2 * kk + 1];
        float mov = offs[pxl * 27 + 18 + kk]    + b_off[18 + kk];

        float m   = 1.f / (1.f + __expf(-mov));
        float py  = (float)(h - 1 + ky) + dyv;
        float px_ = (float)(wpix - 1 + kx) + dxv;
        float fy0 = floorf(py), fx0 = floorf(px_);
        float wy = py - fy0, wx = px_ - fx0;
        int y0 = (int)fy0, x0 = (int)fx0;
        int y1 = y0 + 1, x1 = x0 + 1;
        bool vy0 = (unsigned)y0 < HH, vy1 = (unsigned)y1 < HH;
        bool vx0 = (unsigned)x0 < WW, vx1 = (unsigned)x1 < WW;
        float a00 = (vy0 && vx0) ? (1.f - wy) * (1.f - wx) * m : 0.f;
        float a01 = (vy0 && vx1) ? (1.f - wy) * wx * m : 0.f;
        float a10 = (vy1 && vx0) ? wy * (1.f - wx) * m : 0.f;
        float a11 = (vy1 && vx1) ? wy * wx * m : 0.f;
        int cy0 = min(max(y0, 0), HH - 1), cy1 = min(max(y1, 0), HH - 1);
        int cx0 = min(max(x0, 0), WW - 1), cx1 = min(max(x1, 0), WW - 1);
        const unsigned o00 = ((unsigned)(cy0 * WW + cx0)) << 6;
        const unsigned o01 = ((unsigned)(cy0 * WW + cx1)) << 6;
        const unsigned o10 = ((unsigned)(cy1 * WW + cx0)) << 6;
        const unsigned o11 = ((unsigned)(cy1 * WW + cx1)) << 6;

        u32x4 g00a = *(const u32x4*)(xbq + o00);
        u32x4 g01a = *(const u32x4*)(xbq + o01);
        u32x4 g10a = *(const u32x4*)(xbq + o10);
        u32x4 g11a = *(const u32x4*)(xbq + o11);
        u32x4 g00b = *(const u32x4*)(xbq + o00 + 32);
        u32x4 g01b = *(const u32x4*)(xbq + o01 + 32);
        u32x4 g10b = *(const u32x4*)(xbq + o10 + 32);
        u32x4 g11b = *(const u32x4*)(xbq + o11 + 32);

        const bf16x8* wb = (const bf16x8*)w_bf + (size_t)(kk * 8) * 64;
        bf16x8 A[8];
#pragma unroll
        for (int q = 0; q < 8; q++) A[q] = wb[q * 64 + lane];

        bf16x8 B0, B1;
#pragma unroll
        for (int d = 0; d < 4; d++) {
            float tl = a00 * bfl(g00a[d]) + a01 * bfl(g01a[d])
                     + a10 * bfl(g10a[d]) + a11 * bfl(g11a[d]);
            float th = a00 * bfh(g00a[d]) + a01 * bfh(g01a[d])
                     + a10 * bfh(g10a[d]) + a11 * bfh(g11a[d]);
            B0[2 * d]     = (short)f2bf(tl);
            B0[2 * d + 1] = (short)f2bf(th);
            float ul = a00 * bfl(g00b[d]) + a01 * bfl(g01b[d])
                     + a10 * bfl(g10b[d]) + a11 * bfl(g11b[d]);
            float uh = a00 * bfh(g00b[d]) + a01 * bfh(g01b[d])
                     + a10 * bfh(g10b[d]) + a11 * bfh(g11b[d]);
            B1[2 * d]     = (short)f2bf(ul);
            B1[2 * d + 1] = (short)f2bf(uh);
        }

#pragma unroll
        for (int t = 0; t < 4; t++) {
            acc[t] = __builtin_amdgcn_mfma_f32_16x16x32_bf16(A[t * 2 + 0], B0, acc[t], 0, 0, 0);
            acc[t] = __builtin_amdgcn_mfma_f32_16x16x32_bf16(A[t * 2 + 1], B1, acc[t], 0, 0, 0);
        }
    }

    // ---- output write: px = wave*16 + pxin, co = t*16 + quad*4 + r ----
#pragma unroll
    for (int t = 0; t < 4; t++) {
#pragma unroll
        for (int r = 0; r < 4; r++) {
            int co = t * 16 + quad * 4 + r;
            out[(((size_t)b * CHO + co) * HH + h) * WW + wpix] = acc[t][r];
        }
    }

    // ---- fused per-block channel stats (R18-exact) ----
#pragma unroll
    for (int t = 0; t < 4; t++) {
#pragma unroll
        for (int r = 0; r < 4; r++) {
            float s  = acc[t][r];
            float s2 = s * s;
#pragma unroll
            for (int mk = 1; mk < 16; mk <<= 1) {
                s  += __shfl_xor(s, mk, 64);
                s2 += __shfl_xor(s2, mk, 64);
            }
            if (pxin == 0) {
                int co = t * 16 + quad * 4 + r;
                red[(0 * 4 + wave) * 64 + co] = s;
                red[(1 * 4 + wave) * 64 + co] = s2;
            }
        }
    }
    __syncthreads();
    if (tid < 128) {
        int part = tid >> 6, idx = tid & 63;
        float v = red[(part * 4 + 0) * 64 + idx] + red[(part * 4 + 1) * 64 + idx]
                + red[(part * 4 + 2) * 64 + idx] + red[(part * 4 + 3) * 64 + idx];
        pstats[(size_t)(part * 64 + idx) * 1024 + id] = v;   // transposed: coalesced reduce
    }
}

// ---------------- fused stats-reduce + BN + ReLU ----------------
// Verbatim R18 (passing).
__global__ __launch_bounds__(256) void statsbn_kernel(float* __restrict__ y,
                                                      const float* __restrict__ pstats,
                                                      const float* __restrict__ bias,
                                                      const float* __restrict__ gamma,
                                                      const float* __restrict__ beta) {
    const int co  = blockIdx.x & 63;
    const int seg = blockIdx.x >> 6;           // 0..7
    const int t   = threadIdx.x;

    const float* ps  = pstats + (size_t)co * 1024;
    const float* ps2 = pstats + (size_t)(64 + co) * 1024;
    float s  = ps[t]  + ps[t + 256]  + ps[t + 512]  + ps[t + 768];
    float s2 = ps2[t] + ps2[t + 256] + ps2[t + 512] + ps2[t + 768];
#pragma unroll
    for (int o = 32; o > 0; o >>= 1) {
        s  += __shfl_down(s, o, 64);
        s2 += __shfl_down(s2, o, 64);
    }
    __shared__ float ls[8];
    int lane = t & 63, wv = t >> 6;
    if (lane == 0) { ls[wv] = s; ls[4 + wv] = s2; }
    __syncthreads();
    float S0 = ls[0] + ls[1] + ls[2] + ls[3];
    float S2 = ls[4] + ls[5] + ls[6] + ls[7];
    float bi = bias[co];
    float Sb  = S0 + 65536.f * bi;                       // sum(v+b)
    float S2b = S2 + 2.f * bi * S0 + 65536.f * bi * bi;  // sum((v+b)^2)
    const float inv_n = 1.f / 65536.f;
    float mean = Sb * inv_n;
    float var  = S2b * inv_n - mean * mean;
    float sc = gamma[co] * rsqrtf(var + EPSV);
    float sh = beta[co] - mean * sc + bi * sc;           // y stored raw

    const int b = seg >> 1, half = seg & 1;
    float4* p = (float4*)(y + ((size_t)(b * CHO + co)) * PLANE + half * 8192);
#pragma unroll
    for (int it = 0; it < 8; it++) {
        float4 v = p[it * 256 + t];
        v.x = fmaxf(fmaf(v.x, sc, sh), 0.f);
        v.y = fmaxf(fmaf(v.y, sc, sh), 0.f);
        v.z = fmaxf(fmaf(v.z, sc, sh), 0.f);
        v.w = fmaxf(fmaf(v.w, sc, sh), 0.f);
        p[it * 256 + t] = v;
    }
}

extern "C" void kernel_launch(void* const* d_in, const int* in_sizes, int n_in,
                              void* d_out, int out_size, void* d_ws, size_t ws_size,
                              hipStream_t stream) {
    const float* x     = (const float*)d_in[0];
    const float* w_off = (const float*)d_in[1];
    const float* b_off = (const float*)d_in[2];
    const float* wmat  = (const float*)d_in[3];
    const float* bvec  = (const float*)d_in[4];
    const float* gamma = (const float*)d_in[5];
    const float* beta  = (const float*)d_in[6];
    float* out = (float*)d_out;

    char* ws = (char*)d_ws;
    unsigned short* w_bf  = (unsigned short*)(ws + 1024);   // 73728 B
    unsigned short* woA   = (unsigned short*)(ws + 74752);  // 36864 B
    unsigned short* x_bf  = (unsigned short*)(ws + 139264); // 8388608 B
    float* pstats         = (float*)(ws + 8527872);         // 524288 B -> 9052160 total

    prep_kernel<<<656, 256, 0, stream>>>(x, wmat, w_off, x_bf, w_bf, woA);
    deform_kernel<<<1024, 256, 0, stream>>>(x_bf, w_bf, woA, b_off, out, pstats);
    statsbn_kernel<<<512, 256, 0, stream>>>(out, pstats, bvec, gamma, beta);
}

// Round 13
// 137.215 us; speedup vs baseline: 1.8841x; 1.0462x over previous
//
#include <hip/hip_runtime.h>
#include <math.h>

#define CHI 64
#define CHO 64
#define HH 128
#define WW 128
#define NB 4
#define KK 9
#define NOFF 27
#define EPSV 1e-5f
#define PLANE (HH * WW)
#define SP 72                 // LDS ci-stride (shorts)

typedef float f32x4 __attribute__((ext_vector_type(4)));
typedef short bf16x8 __attribute__((ext_vector_type(8)));
typedef unsigned int u32x4 __attribute__((ext_vector_type(4)));

// fp32 -> bf16 round-to-nearest-even
__device__ __forceinline__ unsigned short f2bf(float f) {
    unsigned u = __float_as_uint(f);
    u += 0x7fff + ((u >> 16) & 1);
    return (unsigned short)(u >> 16);
}
__device__ __forceinline__ float bfl(unsigned u) { return __uint_as_float(u << 16); }
__device__ __forceinline__ float bfh(unsigned u) { return __uint_as_float(u & 0xffff0000u); }

// ---------------- fused prep: x-transpose (blocks 0..511) + weight pack (512..655) ----
// R6-EXACT. Dense-transpose variants poison deform's cache state (R7/R9).
__global__ __launch_bounds__(256) void prep_kernel(const float* __restrict__ x,
                                                   const float* __restrict__ w,
                                                   const float* __restrict__ w_off,
                                                   unsigned short* __restrict__ x_bf,
                                                   unsigned short* __restrict__ w_bf,
                                                   unsigned short* __restrict__ woA) {
    __shared__ unsigned short lt[128 * SP];    // 18432 B
    if (blockIdx.x < 512) {
        const int id = blockIdx.x;             // b*128 + y
        const int b  = id >> 7;
        const int y  = id & 127;
        const int t  = threadIdx.x;
        const int ci = t >> 2, qx = t & 3;
        const float* src = x + ((size_t)(b * CHI + ci)) * PLANE + y * WW;
#pragma unroll
        for (int it = 0; it < 8; it++) {
            int xcol = (it * 4 + qx) * 4;
            float4 v = *(const float4*)(src + xcol);
            lt[(xcol + 0) * SP + ci] = f2bf(v.x);
            lt[(xcol + 1) * SP + ci] = f2bf(v.y);
            lt[(xcol + 2) * SP + ci] = f2bf(v.z);
            lt[(xcol + 3) * SP + ci] = f2bf(v.w);
        }
        __syncthreads();
        unsigned short* dst = x_bf + (size_t)id * (WW * 64);
#pragma unroll
        for (int it = 0; it < 4; it++) {
            int px  = it * 32 + (t >> 3);
            int ci8 = t & 7;
            u32x4 v = *(const u32x4*)&lt[px * SP + ci8 * 8];
            *(u32x4*)(dst + px * 64 + ci8 * 8) = v;
        }
    } else {
        int i = (blockIdx.x - 512) * 256 + threadIdx.x;   // 144*256 = 36864 exactly
        {
            int j    = i & 7;
            int lane = (i >> 3) & 63;
            int ks   = (i >> 9) & 1;
            int ct   = (i >> 10) & 3;
            int kk   = i >> 12;                // 0..8
            int co   = ct * 16 + (lane & 15);
            int ci   = ks * 32 + ((lane >> 4) & 3) * 8 + j;
            w_bf[i]  = f2bf(w[(co * CHI + ci) * KK + kk]);
        }
        if (i < 18432) {
            int j    = i & 7;
            int lane = (i >> 3) & 63;
            int ct   = (i >> 9) & 1;
            int ks   = (i >> 10) & 1;
            int kk   = i >> 11;                // 0..8
            int c    = ct * 16 + (lane & 15);
            int ci   = ks * 32 + (lane >> 4) * 8 + j;
            woA[i]   = (c < NOFF) ? f2bf(w_off[(c * CHI + ci) * KK + kk]) : (unsigned short)0;
        }
    }
}

// ---------------- deform (R25 = R18 base + software-pipelined main loop) ----
// R18-exact structure (halo off-conv with xs staging -- R24 proved it beats
// gather-style by 6us; grid 1024, (256,4), the proven no-spill point).
// ONE change: the main gather loop is software-pipelined. Per kk the critical
// chain was params(40 VALU) -> 8 gathers -> vmcnt wait -> combine -> MFMA,
// fully serialized. Now: params(kk+1) computes WHILE kk's gathers fly;
// gathers(kk+1) issue into the just-freed g-registers right after combine(kk),
// so A-loads + 8 MFMAs + next params cover their latency. No barriers in the
// loop -> loads legally stay in flight across iterations (unlike R13's
// barrier-drained attempt). Scalars only, full unroll (rule: no runtime-
// indexed arrays -> no scratch). Reg budget: (256,4) allows 128/wave,
// R18 used 64 -> headroom for the extra stage.
__global__ __launch_bounds__(256, 4) void deform_kernel(const unsigned short* __restrict__ x_bf,
                                                        const unsigned short* __restrict__ w_bf,
                                                        const unsigned short* __restrict__ woA,
                                                        const float* __restrict__ b_off,
                                                        float* __restrict__ out,
                                                        float* __restrict__ pstats) {
    const int id    = blockIdx.x;              // 0..1023
    const int slot  = id & 7;
    const int b     = slot >> 1;
    const int rb    = id >> 3;                 // 0..127
    const int h     = (slot & 1) * 64 + (rb >> 1);
    const int whalf = rb & 1;
    const int w0    = whalf * 64;
    const int tid   = threadIdx.x;
    const int lane  = tid & 63;
    const int wave  = __builtin_amdgcn_readfirstlane(tid >> 6);
    const int quad  = lane >> 4, pxin = lane & 15;
    const int pxl   = wave * 16 + pxin;        // block-local pixel 0..63
    const int wpix  = w0 + pxl;                // this lane's x coordinate

    __shared__ __align__(16) unsigned short xs[3 * 66 * SP];  // 28512 B
    __shared__ float offs[64 * 27];                           // 6912 B, stride 27
    __shared__ float red[512];                                // 2048 B

    // ---- stage 3x66x64 halo tile from x_bf (dense 16B) ----
    const unsigned short* xb = x_bf + (size_t)b * (PLANE * 64);
#pragma unroll
    for (int ky = 0; ky < 3; ky++) {
        int hr = h - 1 + ky;
        for (int base = tid; base < 528; base += 256) {          // 66 cols x 8 ci-blocks
            int col = base >> 3, ci8 = base & 7;
            int wc  = w0 - 1 + col;
            bool ok = ((unsigned)hr < HH) && ((unsigned)wc < WW);
            u32x4 v = {0u, 0u, 0u, 0u};
            if (ok) v = *(const u32x4*)(xb + ((size_t)(hr * WW + wc)) * 64 + ci8 * 8);
            *(u32x4*)&xs[(ky * 66 + col) * SP + ci8 * 8] = v;
        }
    }
    __syncthreads();

    // ---- offset conv: 36 MFMAs/wave -> 27 channels x this wave's 16 px ----
    f32x4 oacc0 = {0.f, 0.f, 0.f, 0.f};
    f32x4 oacc1 = {0.f, 0.f, 0.f, 0.f};
#pragma unroll 3
    for (int kk = 0; kk < KK; kk++) {
        const int ky = kk / 3, kx = kk - ky * 3;
#pragma unroll
        for (int ks = 0; ks < 2; ks++) {
            const bf16x8* wa = (const bf16x8*)woA + (size_t)((kk * 2 + ks) * 2) * 64;
            bf16x8 A0 = wa[lane];
            bf16x8 A1 = wa[64 + lane];
            bf16x8 B = *(const bf16x8*)&xs[(ky * 66 + wave * 16 + pxin + kx) * SP
                                           + ks * 32 + quad * 8];
            oacc0 = __builtin_amdgcn_mfma_f32_16x16x32_bf16(A0, B, oacc0, 0, 0, 0);
            oacc1 = __builtin_amdgcn_mfma_f32_16x16x32_bf16(A1, B, oacc1, 0, 0, 0);
        }
    }

    // ---- park offsets in LDS: offs[px_local][ch], stride 27 (conflict-free) ----
#pragma unroll
    for (int r = 0; r < 4; r++) {
        int c0 = quad * 4 + r;
        offs[pxl * 27 + c0] = oacc0[r];
        int c1 = 16 + quad * 4 + r;
        if (c1 < NOFF) offs[pxl * 27 + c1] = oacc1[r];
    }
    __syncthreads();

    // ---- main gather + MFMA loop, software-pipelined ----
    f32x4 acc[4];
#pragma unroll
    for (int t = 0; t < 4; t++) acc[t] = (f32x4){0.f, 0.f, 0.f, 0.f};

    const unsigned short* xbq = xb + quad * 8;

    // pipeline registers: params (a,o) and gather batch (g)
    float a00, a01, a10, a11;
    unsigned o00, o01, o10, o11;
    u32x4 g00a, g01a, g10a, g11a, g00b, g01b, g10b, g11b;

    auto mkparams = [&](int kk) {
        const int ky = kk / 3, kx = kk - ky * 3;
        float dyv = offs[pxl * 27 + 2 * kk]     + b_off[2 * kk];
        float dxv = offs[pxl * 27 + 2 * kk + 1] + b_off[2 * kk + 1];
        float mov = offs[pxl * 27 + 18 + kk]    + b_off[18 + kk];
        float m   = 1.f / (1.f + __expf(-mov));
        float py  = (float)(h - 1 + ky) + dyv;
        float px_ = (float)(wpix - 1 + kx) + dxv;
        float fy0 = floorf(py), fx0 = floorf(px_);
        float wy = py - fy0, wx = px_ - fx0;
        int y0 = (int)fy0, x0 = (int)fx0;
        int y1 = y0 + 1, x1 = x0 + 1;
        bool vy0 = (unsigned)y0 < HH, vy1 = (unsigned)y1 < HH;
        bool vx0 = (unsigned)x0 < WW, vx1 = (unsigned)x1 < WW;
        a00 = (vy0 && vx0) ? (1.f - wy) * (1.f - wx) * m : 0.f;
        a01 = (vy0 && vx1) ? (1.f - wy) * wx * m : 0.f;
        a10 = (vy1 && vx0) ? wy * (1.f - wx) * m : 0.f;
        a11 = (vy1 && vx1) ? wy * wx * m : 0.f;
        int cy0 = min(max(y0, 0), HH - 1), cy1 = min(max(y1, 0), HH - 1);
        int cx0 = min(max(x0, 0), WW - 1), cx1 = min(max(x1, 0), WW - 1);
        o00 = ((unsigned)(cy0 * WW + cx0)) << 6;
        o01 = ((unsigned)(cy0 * WW + cx1)) << 6;
        o10 = ((unsigned)(cy1 * WW + cx0)) << 6;
        o11 = ((unsigned)(cy1 * WW + cx1)) << 6;
    };
    auto issue = [&]() {
        g00a = *(const u32x4*)(xbq + o00);
        g01a = *(const u32x4*)(xbq + o01);
        g10a = *(const u32x4*)(xbq + o10);
        g11a = *(const u32x4*)(xbq + o11);
        g00b = *(const u32x4*)(xbq + o00 + 32);
        g01b = *(const u32x4*)(xbq + o01 + 32);
        g10b = *(const u32x4*)(xbq + o10 + 32);
        g11b = *(const u32x4*)(xbq + o11 + 32);
    };

    mkparams(0);
    issue();                                   // gathers for kk=0 in flight

#pragma unroll
    for (int kk = 0; kk < KK; kk++) {
        // stash current coefs; compute next params while gathers fly
        float c00 = a00, c01 = a01, c10 = a10, c11 = a11;
        if (kk + 1 < KK) mkparams(kk + 1);

        // combine (vmcnt wait on g) -> B fragments
        bf16x8 B0, B1;
#pragma unroll
        for (int d = 0; d < 4; d++) {
            float tl = c00 * bfl(g00a[d]) + c01 * bfl(g01a[d])
                     + c10 * bfl(g10a[d]) + c11 * bfl(g11a[d]);
            float th = c00 * bfh(g00a[d]) + c01 * bfh(g01a[d])
                     + c10 * bfh(g10a[d]) + c11 * bfh(g11a[d]);
            B0[2 * d]     = (short)f2bf(tl);
            B0[2 * d + 1] = (short)f2bf(th);
            float ul = c00 * bfl(g00b[d]) + c01 * bfl(g01b[d])
                     + c10 * bfl(g10b[d]) + c11 * bfl(g11b[d]);
            float uh = c00 * bfh(g00b[d]) + c01 * bfh(g01b[d])
                     + c10 * bfh(g10b[d]) + c11 * bfh(g11b[d]);
            B1[2 * d]     = (short)f2bf(ul);
            B1[2 * d + 1] = (short)f2bf(uh);
        }

        // g registers now dead: immediately refill with kk+1's gathers so
        // their latency hides under A-loads + 8 MFMAs + next stash/params.
        if (kk + 1 < KK) issue();

        const bf16x8* wb = (const bf16x8*)w_bf + (size_t)(kk * 8) * 64;
        bf16x8 A[8];
#pragma unroll
        for (int q = 0; q < 8; q++) A[q] = wb[q * 64 + lane];

#pragma unroll
        for (int t = 0; t < 4; t++) {
            acc[t] = __builtin_amdgcn_mfma_f32_16x16x32_bf16(A[t * 2 + 0], B0, acc[t], 0, 0, 0);
            acc[t] = __builtin_amdgcn_mfma_f32_16x16x32_bf16(A[t * 2 + 1], B1, acc[t], 0, 0, 0);
        }
    }

    // ---- output write: px = wave*16 + pxin, co = t*16 + quad*4 + r ----
#pragma unroll
    for (int t = 0; t < 4; t++) {
#pragma unroll
        for (int r = 0; r < 4; r++) {
            int co = t * 16 + quad * 4 + r;
            out[(((size_t)b * CHO + co) * HH + h) * WW + wpix] = acc[t][r];
        }
    }

    // ---- fused per-block channel stats (R18-exact) ----
#pragma unroll
    for (int t = 0; t < 4; t++) {
#pragma unroll
        for (int r = 0; r < 4; r++) {
            float s  = acc[t][r];
            float s2 = s * s;
#pragma unroll
            for (int mk = 1; mk < 16; mk <<= 1) {
                s  += __shfl_xor(s, mk, 64);
                s2 += __shfl_xor(s2, mk, 64);
            }
            if (pxin == 0) {
                int co = t * 16 + quad * 4 + r;
                red[(0 * 4 + wave) * 64 + co] = s;
                red[(1 * 4 + wave) * 64 + co] = s2;
            }
        }
    }
    __syncthreads();
    if (tid < 128) {
        int part = tid >> 6, idx = tid & 63;
        float v = red[(part * 4 + 0) * 64 + idx] + red[(part * 4 + 1) * 64 + idx]
                + red[(part * 4 + 2) * 64 + idx] + red[(part * 4 + 3) * 64 + idx];
        pstats[(size_t)(part * 64 + idx) * 1024 + id] = v;   // transposed: coalesced reduce
    }
}

// ---------------- fused stats-reduce + BN + ReLU ----------------
// Verbatim R18 (passing).
__global__ __launch_bounds__(256) void statsbn_kernel(float* __restrict__ y,
                                                      const float* __restrict__ pstats,
                                                      const float* __restrict__ bias,
                                                      const float* __restrict__ gamma,
                                                      const float* __restrict__ beta) {
    const int co  = blockIdx.x & 63;
    const int seg = blockIdx.x >> 6;           // 0..7
    const int t   = threadIdx.x;

    const float* ps  = pstats + (size_t)co * 1024;
    const float* ps2 = pstats + (size_t)(64 + co) * 1024;
    float s  = ps[t]  + ps[t + 256]  + ps[t + 512]  + ps[t + 768];
    float s2 = ps2[t] + ps2[t + 256] + ps2[t + 512] + ps2[t + 768];
#pragma unroll
    for (int o = 32; o > 0; o >>= 1) {
        s  += __shfl_down(s, o, 64);
        s2 += __shfl_down(s2, o, 64);
    }
    __shared__ float ls[8];
    int lane = t & 63, wv = t >> 6;
    if (lane == 0) { ls[wv] = s; ls[4 + wv] = s2; }
    __syncthreads();
    float S0 = ls[0] + ls[1] + ls[2] + ls[3];
    float S2 = ls[4] + ls[5] + ls[6] + ls[7];
    float bi = bias[co];
    float Sb  = S0 + 65536.f * bi;                       // sum(v+b)
    float S2b = S2 + 2.f * bi * S0 + 65536.f * bi * bi;  // sum((v+b)^2)
    const float inv_n = 1.f / 65536.f;
    float mean = Sb * inv_n;
    float var  = S2b * inv_n - mean * mean;
    float sc = gamma[co] * rsqrtf(var + EPSV);
    float sh = beta[co] - mean * sc + bi * sc;           // y stored raw

    const int b = seg >> 1, half = seg & 1;
    float4* p = (float4*)(y + ((size_t)(b * CHO + co)) * PLANE + half * 8192);
#pragma unroll
    for (int it = 0; it < 8; it++) {
        float4 v = p[it * 256 + t];
        v.x = fmaxf(fmaf(v.x, sc, sh), 0.f);
        v.y = fmaxf(fmaf(v.y, sc, sh), 0.f);
        v.z = fmaxf(fmaf(v.z, sc, sh), 0.f);
        v.w = fmaxf(fmaf(v.w, sc, sh), 0.f);
        p[it * 256 + t] = v;
    }
}

extern "C" void kernel_launch(void* const* d_in, const int* in_sizes, int n_in,
                              void* d_out, int out_size, void* d_ws, size_t ws_size,
                              hipStream_t stream) {
    const float* x     = (const float*)d_in[0];
    const float* w_off = (const float*)d_in[1];
    const float* b_off = (const float*)d_in[2];
    const float* wmat  = (const float*)d_in[3];
    const float* bvec  = (const float*)d_in[4];
    const float* gamma = (const float*)d_in[5];
    const float* beta  = (const float*)d_in[6];
    float* out = (float*)d_out;

    char* ws = (char*)d_ws;
    unsigned short* w_bf  = (unsigned short*)(ws + 1024);   // 73728 B
    unsigned short* woA   = (unsigned short*)(ws + 74752);  // 36864 B
    unsigned short* x_bf  = (unsigned short*)(ws + 139264); // 8388608 B
    float* pstats         = (float*)(ws + 8527872);         // 524288 B -> 9052160 total

    prep_kernel<<<656, 256, 0, stream>>>(x, wmat, w_off, x_bf, w_bf, woA);
    deform_kernel<<<1024, 256, 0, stream>>>(x_bf, w_bf, woA, b_off, out, pstats);
    statsbn_kernel<<<512, 256, 0, stream>>>(out, pstats, bvec, gamma, beta);
}